// Round 1
// baseline (5135.873 us; speedup 1.0000x reference)
//
#include <hip/hip_runtime.h>
#include <math.h>

#define D_IN 64
#define D_H 40
#define D_OUT 24

// ---------------- Layer-1 edge scatter: sum[dst] += x[src], cnt[dst] += 1 ----
// 16 threads per edge, each handles one float4 (4 atomics).
__global__ void scatter1(const float* __restrict__ x,
                         const int* __restrict__ src,
                         const int* __restrict__ dst,
                         float* __restrict__ sum,
                         float* __restrict__ cnt,
                         int nthreads) {
    int tid = blockIdx.x * blockDim.x + threadIdx.x;
    if (tid >= nthreads) return;
    int e = tid >> 4;
    int q = tid & 15;
    int s = src[e];
    int d = dst[e];
    float4 v = ((const float4*)x)[s * 16 + q];
    float* o = sum + (size_t)d * D_IN + q * 4;
    atomicAdd(o + 0, v.x);
    atomicAdd(o + 1, v.y);
    atomicAdd(o + 2, v.z);
    atomicAdd(o + 3, v.w);
    if (q == 0) atomicAdd(cnt + d, 1.0f);
}

// ---------------- Layer-1 node update: h = relu(agg@W1l^T + b1 + x@W1r^T) ----
// 4 nodes per 256-thread block; 64 lanes per node.
__global__ void node1(const float* __restrict__ x,
                      const float* __restrict__ sum,
                      const float* __restrict__ cnt,
                      const float* __restrict__ W1l,
                      const float* __restrict__ b1,
                      const float* __restrict__ W1r,
                      float* __restrict__ h,
                      int n_nodes) {
    __shared__ __align__(16) float xs[4][D_IN];
    __shared__ __align__(16) float as[4][D_IN];
    int local = threadIdx.x >> 6;
    int lane  = threadIdx.x & 63;
    int node  = blockIdx.x * 4 + local;
    bool valid = node < n_nodes;
    if (valid) {
        float c   = cnt[node];
        float inv = 1.0f / fmaxf(c, 1.0f);
        xs[local][lane] = x[(size_t)node * D_IN + lane];
        as[local][lane] = sum[(size_t)node * D_IN + lane] * inv;
    }
    __syncthreads();
    if (valid && lane < D_H) {
        const float4* wr = (const float4*)(W1r + lane * D_IN);
        const float4* wl = (const float4*)(W1l + lane * D_IN);
        const float4* xr = (const float4*)xs[local];
        const float4* ar = (const float4*)as[local];
        float acc = b1[lane];
        #pragma unroll
        for (int k = 0; k < D_IN / 4; ++k) {
            float4 w0 = wr[k], xv = xr[k];
            acc += w0.x * xv.x + w0.y * xv.y + w0.z * xv.z + w0.w * xv.w;
            float4 w1 = wl[k], av = ar[k];
            acc += w1.x * av.x + w1.y * av.y + w1.z * av.z + w1.w * av.w;
        }
        h[(size_t)node * D_H + lane] = fmaxf(acc, 0.0f);
    }
}

// ---------------- Layer-2 edge scatter: sum[dst] += h[src] -------------------
// 10 threads per edge, each one float4 (40 floats per row).
__global__ void scatter2(const float* __restrict__ h,
                         const int* __restrict__ src,
                         const int* __restrict__ dst,
                         float* __restrict__ sum,
                         int nthreads) {
    int tid = blockIdx.x * blockDim.x + threadIdx.x;
    if (tid >= nthreads) return;
    int e = tid / 10;
    int q = tid - e * 10;
    int s = src[e];
    int d = dst[e];
    float4 v = *(const float4*)(h + (size_t)s * D_H + q * 4);
    float* o = sum + (size_t)d * D_H + q * 4;
    atomicAdd(o + 0, v.x);
    atomicAdd(o + 1, v.y);
    atomicAdd(o + 2, v.z);
    atomicAdd(o + 3, v.w);
}

// ---------------- Layer-2 node update + log_softmax --------------------------
__global__ void node2(const float* __restrict__ h,
                      const float* __restrict__ sum,
                      const float* __restrict__ cnt,
                      const float* __restrict__ W2l,
                      const float* __restrict__ b2,
                      const float* __restrict__ W2r,
                      float* __restrict__ out,
                      int n_nodes) {
    __shared__ float hs[4][D_H];
    __shared__ float as[4][D_H];
    __shared__ float os[4][D_OUT];
    int local = threadIdx.x >> 6;
    int lane  = threadIdx.x & 63;
    int node  = blockIdx.x * 4 + local;
    bool valid = node < n_nodes;
    if (valid && lane < D_H) {
        float inv = 1.0f / fmaxf(cnt[node], 1.0f);
        hs[local][lane] = h[(size_t)node * D_H + lane];
        as[local][lane] = sum[(size_t)node * D_H + lane] * inv;
    }
    __syncthreads();
    if (valid && lane < D_OUT) {
        const float* wl = W2l + lane * D_H;
        const float* wr = W2r + lane * D_H;
        float acc = b2[lane];
        #pragma unroll
        for (int k = 0; k < D_H; ++k)
            acc += wl[k] * as[local][k] + wr[k] * hs[local][k];
        os[local][lane] = acc;
    }
    __syncthreads();
    if (valid && lane < D_OUT) {
        float m = -INFINITY;
        #pragma unroll
        for (int k = 0; k < D_OUT; ++k) m = fmaxf(m, os[local][k]);
        float se = 0.0f;
        #pragma unroll
        for (int k = 0; k < D_OUT; ++k) se += expf(os[local][k] - m);
        out[(size_t)node * D_OUT + lane] = os[local][lane] - m - logf(se);
    }
}

extern "C" void kernel_launch(void* const* d_in, const int* in_sizes, int n_in,
                              void* d_out, int out_size, void* d_ws, size_t ws_size,
                              hipStream_t stream) {
    const float* x   = (const float*)d_in[0];
    const int*   ei  = (const int*)d_in[1];
    const float* W1l = (const float*)d_in[2];
    const float* b1  = (const float*)d_in[3];
    const float* W1r = (const float*)d_in[4];
    const float* W2l = (const float*)d_in[5];
    const float* b2  = (const float*)d_in[6];
    const float* W2r = (const float*)d_in[7];
    float* out = (float*)d_out;

    const int n = in_sizes[0] / D_IN;      // 100000
    const int E = in_sizes[1] / 2;         // 3200000
    const int* src = ei;
    const int* dst = ei + E;

    // Workspace: [h: n*40 f32][cnt: n f32][sum: n*64 f32 (reused as n*40 in L2)]
    char* ws = (char*)d_ws;
    float* h   = (float*)ws;
    float* cnt = (float*)(ws + (size_t)n * D_H * 4);
    float* sum = (float*)(ws + (size_t)n * (D_H + 1) * 4);

    // zero cnt + sum (contiguous)
    hipMemsetAsync(cnt, 0, (size_t)n * (1 + D_IN) * 4, stream);

    int t1 = E * 16;
    scatter1<<<(t1 + 255) / 256, 256, 0, stream>>>(x, src, dst, sum, cnt, t1);

    node1<<<(n + 3) / 4, 256, 0, stream>>>(x, sum, cnt, W1l, b1, W1r, h, n);

    hipMemsetAsync(sum, 0, (size_t)n * D_H * 4, stream);

    int t2 = E * 10;
    scatter2<<<(t2 + 255) / 256, 256, 0, stream>>>(h, src, dst, sum, t2);

    node2<<<(n + 3) / 4, 256, 0, stream>>>(h, sum, cnt, W2l, b2, W2r, out, n);
}

// Round 2
// 1140.337 us; speedup vs baseline: 4.5038x; 4.5038x over previous
//
#include <hip/hip_runtime.h>
#include <math.h>

#define D_IN 64
#define D_H 40
#define D_OUT 24

// ---------------- CSR build ----------------
__global__ void hist_kernel(const int* __restrict__ dst, int* __restrict__ deg, int E) {
    int i = blockIdx.x * blockDim.x + threadIdx.x;
    if (i < E) atomicAdd(&deg[dst[i]], 1);
}

// Per-256-block exclusive scan; block totals to bsum.
__global__ void scan_blocks(const int* __restrict__ deg, int* __restrict__ off,
                            int* __restrict__ bsum, int n) {
    __shared__ int s[256];
    int tx = threadIdx.x;
    int i = blockIdx.x * 256 + tx;
    int v = (i < n) ? deg[i] : 0;
    s[tx] = v;
    __syncthreads();
    for (int d = 1; d < 256; d <<= 1) {
        int t = (tx >= d) ? s[tx - d] : 0;
        __syncthreads();
        s[tx] += t;
        __syncthreads();
    }
    if (i < n) off[i] = s[tx] - v;           // exclusive within block
    if (tx == 255) bsum[blockIdx.x] = s[255];
}

// Single-wave scan of block sums (nb <= ~4096 fine); writes off[n] = total.
__global__ void scan_tops(int* __restrict__ bsum, int nb, int* __restrict__ off, int n) {
    int lane = threadIdx.x & 63;
    int carry = 0;
    for (int base = 0; base < nb; base += 64) {
        int i = base + lane;
        int orig = (i < nb) ? bsum[i] : 0;
        int v = orig;
        #pragma unroll
        for (int d = 1; d < 64; d <<= 1) {
            int t = __shfl_up(v, d);
            if (lane >= d) v += t;
        }
        if (i < nb) bsum[i] = carry + v - orig;  // exclusive
        carry += __shfl(v, 63);
    }
    if (lane == 0) off[n] = carry;
}

__global__ void add_offsets(int* __restrict__ off, const int* __restrict__ bsum, int n) {
    int i = blockIdx.x * blockDim.x + threadIdx.x;
    if (i < n) off[i] += bsum[i >> 8];
}

__global__ void placement(const int* __restrict__ src, const int* __restrict__ dst,
                          const int* __restrict__ off, int* __restrict__ cursor,
                          int* __restrict__ csr, int E) {
    int i = blockIdx.x * blockDim.x + threadIdx.x;
    if (i < E) {
        int d = dst[i];
        int pos = off[d] + atomicAdd(&cursor[d], 1);
        csr[pos] = src[i];
    }
}

// ---------------- Layer 1: gather(mean) + linear + relu ----------------
// 4 waves/block, one node per wave, lane = feature dim (64).
__global__ void gather_node1(const float* __restrict__ x,
                             const int* __restrict__ off,
                             const int* __restrict__ csr,
                             const float* __restrict__ W1l,
                             const float* __restrict__ b1,
                             const float* __restrict__ W1r,
                             float* __restrict__ h, int n) {
    __shared__ __align__(16) float xs[4][D_IN];
    __shared__ __align__(16) float as[4][D_IN];
    int local = threadIdx.x >> 6;
    int lane  = threadIdx.x & 63;
    int node  = blockIdx.x * 4 + local;
    if (node < n) {
        int o0 = off[node], o1 = off[node + 1];
        float acc = 0.0f;
        for (int base = o0; base < o1; base += 64) {
            int cnt = min(64, o1 - base);
            int idx = (base + lane < o1) ? csr[base + lane] : 0;
            for (int j = 0; j < cnt; ++j) {
                int s = __shfl(idx, j);
                acc += x[(size_t)s * D_IN + lane];
            }
        }
        float inv = 1.0f / fmaxf((float)(o1 - o0), 1.0f);
        as[local][lane] = acc * inv;
        xs[local][lane] = x[(size_t)node * D_IN + lane];
    }
    __syncthreads();
    if (node < n && lane < D_H) {
        const float4* wr = (const float4*)(W1r + lane * D_IN);
        const float4* wl = (const float4*)(W1l + lane * D_IN);
        const float4* xr = (const float4*)xs[local];
        const float4* ar = (const float4*)as[local];
        float acc = b1[lane];
        #pragma unroll
        for (int k = 0; k < D_IN / 4; ++k) {
            float4 w0 = wr[k], xv = xr[k];
            acc += w0.x * xv.x + w0.y * xv.y + w0.z * xv.z + w0.w * xv.w;
            float4 w1 = wl[k], av = ar[k];
            acc += w1.x * av.x + w1.y * av.y + w1.z * av.z + w1.w * av.w;
        }
        h[(size_t)node * D_H + lane] = fmaxf(acc, 0.0f);
    }
}

// ---------------- Layer 2: gather(mean) + linear + log_softmax ----------------
__global__ void gather_node2(const float* __restrict__ h,
                             const int* __restrict__ off,
                             const int* __restrict__ csr,
                             const float* __restrict__ W2l,
                             const float* __restrict__ b2,
                             const float* __restrict__ W2r,
                             float* __restrict__ out, int n) {
    __shared__ float hs[4][D_H];
    __shared__ float as[4][D_H];
    __shared__ float os[4][D_OUT];
    int local = threadIdx.x >> 6;
    int lane  = threadIdx.x & 63;
    int node  = blockIdx.x * 4 + local;
    if (node < n) {
        int o0 = off[node], o1 = off[node + 1];
        float acc = 0.0f;
        for (int base = o0; base < o1; base += 64) {
            int cnt = min(64, o1 - base);
            int idx = (base + lane < o1) ? csr[base + lane] : 0;
            for (int j = 0; j < cnt; ++j) {
                int s = __shfl(idx, j);
                if (lane < D_H) acc += h[(size_t)s * D_H + lane];
            }
        }
        float inv = 1.0f / fmaxf((float)(o1 - o0), 1.0f);
        if (lane < D_H) {
            as[local][lane] = acc * inv;
            hs[local][lane] = h[(size_t)node * D_H + lane];
        }
    }
    __syncthreads();
    if (node < n && lane < D_OUT) {
        const float* wl = W2l + lane * D_H;
        const float* wr = W2r + lane * D_H;
        float acc = b2[lane];
        #pragma unroll
        for (int k = 0; k < D_H; ++k)
            acc += wl[k] * as[local][k] + wr[k] * hs[local][k];
        os[local][lane] = acc;
    }
    __syncthreads();
    if (node < n && lane < D_OUT) {
        float m = -INFINITY;
        #pragma unroll
        for (int k = 0; k < D_OUT; ++k) m = fmaxf(m, os[local][k]);
        float se = 0.0f;
        #pragma unroll
        for (int k = 0; k < D_OUT; ++k) se += expf(os[local][k] - m);
        out[(size_t)node * D_OUT + lane] = os[local][lane] - m - logf(se);
    }
}

extern "C" void kernel_launch(void* const* d_in, const int* in_sizes, int n_in,
                              void* d_out, int out_size, void* d_ws, size_t ws_size,
                              hipStream_t stream) {
    const float* x   = (const float*)d_in[0];
    const int*   ei  = (const int*)d_in[1];
    const float* W1l = (const float*)d_in[2];
    const float* b1  = (const float*)d_in[3];
    const float* W1r = (const float*)d_in[4];
    const float* W2l = (const float*)d_in[5];
    const float* b2  = (const float*)d_in[6];
    const float* W2r = (const float*)d_in[7];
    float* out = (float*)d_out;

    const int n = in_sizes[0] / D_IN;      // 100000
    const int E = in_sizes[1] / 2;         // 3200000
    const int* src = ei;
    const int* dst = ei + E;

    const int nb = (n + 255) / 256;        // scan blocks

    // Workspace layout (bytes):
    //  h:      n*40*4        = 16 MB
    //  off:    (n+1)*4
    //  deg:    n*4
    //  cursor: n*4
    //  bsum:   nb*4
    //  csr:    E*4           = 12.8 MB
    char* ws = (char*)d_ws;
    float* h    = (float*)ws;                       ws += (size_t)n * D_H * 4;
    int*   off  = (int*)ws;                         ws += (size_t)(n + 1) * 4;
    int*   deg  = (int*)ws;                         ws += (size_t)n * 4;
    int*   cur  = (int*)ws;                         ws += (size_t)n * 4;
    int*   bsum = (int*)ws;                         ws += (size_t)nb * 4;
    int*   csr  = (int*)ws;

    // zero deg + cursor (contiguous)
    hipMemsetAsync(deg, 0, (size_t)n * 2 * 4, stream);

    hist_kernel<<<(E + 255) / 256, 256, 0, stream>>>(dst, deg, E);
    scan_blocks<<<nb, 256, 0, stream>>>(deg, off, bsum, n);
    scan_tops<<<1, 64, 0, stream>>>(bsum, nb, off, n);
    add_offsets<<<(n + 255) / 256, 256, 0, stream>>>(off, bsum, n);
    placement<<<(E + 255) / 256, 256, 0, stream>>>(src, dst, off, cur, csr, E);

    gather_node1<<<(n + 3) / 4, 256, 0, stream>>>(x, off, csr, W1l, b1, W1r, h, n);
    gather_node2<<<(n + 3) / 4, 256, 0, stream>>>(h, off, csr, W2l, b2, W2r, out, n);
}

// Round 3
// 895.294 us; speedup vs baseline: 5.7365x; 1.2737x over previous
//
#include <hip/hip_runtime.h>
#include <math.h>

#define D_IN 64
#define D_H 40
#define D_OUT 24

// ---------------- CSR build ----------------
__global__ void hist_kernel(const int* __restrict__ dst, int* __restrict__ deg, int E) {
    int i = blockIdx.x * blockDim.x + threadIdx.x;
    if (i < E) atomicAdd(&deg[dst[i]], 1);
}

__global__ void scan_blocks(const int* __restrict__ deg, int* __restrict__ off,
                            int* __restrict__ bsum, int n) {
    __shared__ int s[256];
    int tx = threadIdx.x;
    int i = blockIdx.x * 256 + tx;
    int v = (i < n) ? deg[i] : 0;
    s[tx] = v;
    __syncthreads();
    for (int d = 1; d < 256; d <<= 1) {
        int t = (tx >= d) ? s[tx - d] : 0;
        __syncthreads();
        s[tx] += t;
        __syncthreads();
    }
    if (i < n) off[i] = s[tx] - v;           // exclusive within block
    if (tx == 255) bsum[blockIdx.x] = s[255];
}

__global__ void scan_tops(int* __restrict__ bsum, int nb, int* __restrict__ off, int n) {
    int lane = threadIdx.x & 63;
    int carry = 0;
    for (int base = 0; base < nb; base += 64) {
        int i = base + lane;
        int orig = (i < nb) ? bsum[i] : 0;
        int v = orig;
        #pragma unroll
        for (int d = 1; d < 64; d <<= 1) {
            int t = __shfl_up(v, d);
            if (lane >= d) v += t;
        }
        if (i < nb) bsum[i] = carry + v - orig;  // exclusive
        carry += __shfl(v, 63);
    }
    if (lane == 0) off[n] = carry;
}

__global__ void add_offsets(int* __restrict__ off, const int* __restrict__ bsum, int n) {
    int i = blockIdx.x * blockDim.x + threadIdx.x;
    if (i < n) off[i] += bsum[i >> 8];
}

__global__ void placement(const int* __restrict__ src, const int* __restrict__ dst,
                          const int* __restrict__ off, int* __restrict__ cursor,
                          int* __restrict__ csr, int E) {
    int i = blockIdx.x * blockDim.x + threadIdx.x;
    if (i < E) {
        int d = dst[i];
        int pos = off[d] + atomicAdd(&cursor[d], 1);
        csr[pos] = src[i];
    }
}

// ---------------- Layer 1: gather(mean) + linear + relu ----------------
// 1 wave/node. Wave = 4 neighbor-groups x 16 lanes; each lane owns one float4
// chunk of the 64-dim row. 4 independent dwordx4 load chains per iteration.
__global__ void gather_node1(const float* __restrict__ x,
                             const int* __restrict__ off,
                             const int* __restrict__ csr,
                             const float* __restrict__ W1l,
                             const float* __restrict__ b1,
                             const float* __restrict__ W1r,
                             float* __restrict__ h, int n) {
    __shared__ __align__(16) float xs[4][D_IN];
    __shared__ __align__(16) float as[4][D_IN];
    int local = threadIdx.x >> 6;
    int lane  = threadIdx.x & 63;
    int g     = lane >> 4;        // neighbor group 0..3
    int q     = lane & 15;        // float4 chunk 0..15
    int node  = blockIdx.x * 4 + local;
    const float4* x4 = (const float4*)x;
    if (node < n) {
        int o0 = off[node], o1 = off[node + 1];
        float4 acc = make_float4(0.f, 0.f, 0.f, 0.f);
        for (int base = o0; base < o1; base += 64) {
            int cnt = min(64, o1 - base);
            int idx = (base + lane < o1) ? csr[base + lane] : 0;
            for (int j = 0; j < cnt; j += 4) {
                int jj = j + g;
                int s = __shfl(idx, jj);
                if (jj < cnt) {
                    float4 v = x4[(size_t)s * 16 + q];
                    acc.x += v.x; acc.y += v.y; acc.z += v.z; acc.w += v.w;
                }
            }
        }
        // reduce across the 4 neighbor groups
        #pragma unroll
        for (int st = 16; st < 64; st <<= 1) {
            acc.x += __shfl_xor(acc.x, st);
            acc.y += __shfl_xor(acc.y, st);
            acc.z += __shfl_xor(acc.z, st);
            acc.w += __shfl_xor(acc.w, st);
        }
        float inv = 1.0f / fmaxf((float)(o1 - o0), 1.0f);
        if (g == 0) {
            float4 m = make_float4(acc.x * inv, acc.y * inv, acc.z * inv, acc.w * inv);
            ((float4*)as[local])[q] = m;
        }
        xs[local][lane] = x[(size_t)node * D_IN + lane];
    }
    __syncthreads();
    if (node < n && lane < D_H) {
        const float4* wr = (const float4*)(W1r + lane * D_IN);
        const float4* wl = (const float4*)(W1l + lane * D_IN);
        const float4* xr = (const float4*)xs[local];
        const float4* ar = (const float4*)as[local];
        float acc = b1[lane];
        #pragma unroll
        for (int k = 0; k < D_IN / 4; ++k) {
            float4 w0 = wr[k], xv = xr[k];
            acc += w0.x * xv.x + w0.y * xv.y + w0.z * xv.z + w0.w * xv.w;
            float4 w1 = wl[k], av = ar[k];
            acc += w1.x * av.x + w1.y * av.y + w1.z * av.z + w1.w * av.w;
        }
        h[(size_t)node * D_H + lane] = fmaxf(acc, 0.0f);
    }
}

// ---------------- Layer 2: gather(mean) + linear + log_softmax ----------------
// Same structure; row = 10 float4s, lanes with (lane&15)<10 active.
__global__ void gather_node2(const float* __restrict__ h,
                             const int* __restrict__ off,
                             const int* __restrict__ csr,
                             const float* __restrict__ W2l,
                             const float* __restrict__ b2,
                             const float* __restrict__ W2r,
                             float* __restrict__ out, int n) {
    __shared__ __align__(16) float hs[4][D_H];
    __shared__ __align__(16) float as[4][D_H];
    __shared__ float os[4][D_OUT];
    int local = threadIdx.x >> 6;
    int lane  = threadIdx.x & 63;
    int g     = lane >> 4;        // neighbor group 0..3
    int t     = lane & 15;        // float4 chunk, active when t<10
    int node  = blockIdx.x * 4 + local;
    const float4* h4 = (const float4*)h;
    if (node < n) {
        int o0 = off[node], o1 = off[node + 1];
        float4 acc = make_float4(0.f, 0.f, 0.f, 0.f);
        for (int base = o0; base < o1; base += 64) {
            int cnt = min(64, o1 - base);
            int idx = (base + lane < o1) ? csr[base + lane] : 0;
            for (int j = 0; j < cnt; j += 4) {
                int jj = j + g;
                int s = __shfl(idx, jj);
                if (jj < cnt && t < 10) {
                    float4 v = h4[(size_t)s * 10 + t];
                    acc.x += v.x; acc.y += v.y; acc.z += v.z; acc.w += v.w;
                }
            }
        }
        #pragma unroll
        for (int st = 16; st < 64; st <<= 1) {
            acc.x += __shfl_xor(acc.x, st);
            acc.y += __shfl_xor(acc.y, st);
            acc.z += __shfl_xor(acc.z, st);
            acc.w += __shfl_xor(acc.w, st);
        }
        float inv = 1.0f / fmaxf((float)(o1 - o0), 1.0f);
        if (g == 0 && t < 10)
            ((float4*)as[local])[t] = make_float4(acc.x * inv, acc.y * inv,
                                                  acc.z * inv, acc.w * inv);
        if (lane < D_H)
            hs[local][lane] = h[(size_t)node * D_H + lane];
    }
    __syncthreads();
    if (node < n && lane < D_OUT) {
        const float* wl = W2l + lane * D_H;
        const float* wr = W2r + lane * D_H;
        float acc = b2[lane];
        #pragma unroll
        for (int k = 0; k < D_H; ++k)
            acc += wl[k] * as[local][k] + wr[k] * hs[local][k];
        os[local][lane] = acc;
    }
    __syncthreads();
    if (node < n && lane < D_OUT) {
        float m = -INFINITY;
        #pragma unroll
        for (int k = 0; k < D_OUT; ++k) m = fmaxf(m, os[local][k]);
        float se = 0.0f;
        #pragma unroll
        for (int k = 0; k < D_OUT; ++k) se += expf(os[local][k] - m);
        out[(size_t)node * D_OUT + lane] = os[local][lane] - m - logf(se);
    }
}

extern "C" void kernel_launch(void* const* d_in, const int* in_sizes, int n_in,
                              void* d_out, int out_size, void* d_ws, size_t ws_size,
                              hipStream_t stream) {
    const float* x   = (const float*)d_in[0];
    const int*   ei  = (const int*)d_in[1];
    const float* W1l = (const float*)d_in[2];
    const float* b1  = (const float*)d_in[3];
    const float* W1r = (const float*)d_in[4];
    const float* W2l = (const float*)d_in[5];
    const float* b2  = (const float*)d_in[6];
    const float* W2r = (const float*)d_in[7];
    float* out = (float*)d_out;

    const int n = in_sizes[0] / D_IN;      // 100000
    const int E = in_sizes[1] / 2;         // 3200000
    const int* src = ei;
    const int* dst = ei + E;

    const int nb = (n + 255) / 256;

    char* ws = (char*)d_ws;
    float* h    = (float*)ws;                       ws += (size_t)n * D_H * 4;
    int*   off  = (int*)ws;                         ws += (size_t)(n + 1) * 4;
    int*   deg  = (int*)ws;                         ws += (size_t)n * 4;
    int*   cur  = (int*)ws;                         ws += (size_t)n * 4;
    int*   bsum = (int*)ws;                         ws += (size_t)nb * 4;
    int*   csr  = (int*)ws;

    hipMemsetAsync(deg, 0, (size_t)n * 2 * 4, stream);

    hist_kernel<<<(E + 255) / 256, 256, 0, stream>>>(dst, deg, E);
    scan_blocks<<<nb, 256, 0, stream>>>(deg, off, bsum, n);
    scan_tops<<<1, 64, 0, stream>>>(bsum, nb, off, n);
    add_offsets<<<(n + 255) / 256, 256, 0, stream>>>(off, bsum, n);
    placement<<<(E + 255) / 256, 256, 0, stream>>>(src, dst, off, cur, csr, E);

    gather_node1<<<(n + 3) / 4, 256, 0, stream>>>(x, off, csr, W1l, b1, W1r, h, n);
    gather_node2<<<(n + 3) / 4, 256, 0, stream>>>(h, off, csr, W2l, b2, W2r, out, n);
}

// Round 4
// 868.867 us; speedup vs baseline: 5.9110x; 1.0304x over previous
//
#include <hip/hip_runtime.h>
#include <math.h>

#define D_IN 64
#define D_H 40
#define D_OUT 24

typedef unsigned int u32;
typedef unsigned short u16;

// ---------------- CSR build ----------------
__global__ void hist_kernel(const int* __restrict__ dst, int* __restrict__ deg, int E) {
    int i = blockIdx.x * blockDim.x + threadIdx.x;
    if (i < E) atomicAdd(&deg[dst[i]], 1);
}

__global__ void scan_blocks(const int* __restrict__ deg, int* __restrict__ off,
                            int* __restrict__ bsum, int n) {
    __shared__ int s[256];
    int tx = threadIdx.x;
    int i = blockIdx.x * 256 + tx;
    int v = (i < n) ? deg[i] : 0;
    s[tx] = v;
    __syncthreads();
    for (int d = 1; d < 256; d <<= 1) {
        int t = (tx >= d) ? s[tx - d] : 0;
        __syncthreads();
        s[tx] += t;
        __syncthreads();
    }
    if (i < n) off[i] = s[tx] - v;           // exclusive within block
    if (tx == 255) bsum[blockIdx.x] = s[255];
}

__global__ void scan_tops(int* __restrict__ bsum, int nb, int* __restrict__ off, int n) {
    int lane = threadIdx.x & 63;
    int carry = 0;
    for (int base = 0; base < nb; base += 64) {
        int i = base + lane;
        int orig = (i < nb) ? bsum[i] : 0;
        int v = orig;
        #pragma unroll
        for (int d = 1; d < 64; d <<= 1) {
            int t = __shfl_up(v, d);
            if (lane >= d) v += t;
        }
        if (i < nb) bsum[i] = carry + v - orig;  // exclusive
        carry += __shfl(v, 63);
    }
    if (lane == 0) off[n] = carry;
}

__global__ void add_offsets(int* __restrict__ off, const int* __restrict__ bsum, int n) {
    int i = blockIdx.x * blockDim.x + threadIdx.x;
    if (i < n) off[i] += bsum[i >> 8];
}

__global__ void placement(const int* __restrict__ src, const int* __restrict__ dst,
                          const int* __restrict__ off, int* __restrict__ cursor,
                          int* __restrict__ csr, int E) {
    int i = blockIdx.x * blockDim.x + threadIdx.x;
    if (i < E) {
        int d = dst[i];
        int pos = off[d] + atomicAdd(&cursor[d], 1);
        csr[pos] = src[i];
    }
}

// ---------------- bf16 helpers ----------------
__device__ inline u16 f32_to_bf16_rne(float f) {
    u32 u = __float_as_uint(f);
    u += 0x7fffu + ((u >> 16) & 1u);
    return (u16)(u >> 16);
}

// accumulate 8 bf16 (packed in uint4) into f32 acc[8]
__device__ inline void accum8(float* a, uint4 w) {
    a[0] += __uint_as_float(w.x << 16);
    a[1] += __uint_as_float(w.x & 0xffff0000u);
    a[2] += __uint_as_float(w.y << 16);
    a[3] += __uint_as_float(w.y & 0xffff0000u);
    a[4] += __uint_as_float(w.z << 16);
    a[5] += __uint_as_float(w.z & 0xffff0000u);
    a[6] += __uint_as_float(w.w << 16);
    a[7] += __uint_as_float(w.w & 0xffff0000u);
}

// ---------------- pre1: xl = bf16(x @ W1l^T) ----------------
__global__ void pre1(const float* __restrict__ x, const float* __restrict__ W1l,
                     u16* __restrict__ xl, int n) {
    __shared__ __align__(16) float xs[4][D_IN];
    int local = threadIdx.x >> 6;
    int lane  = threadIdx.x & 63;
    int node  = blockIdx.x * 4 + local;
    if (node < n) xs[local][lane] = x[(size_t)node * D_IN + lane];
    __syncthreads();
    if (node < n && lane < D_H) {
        const float4* w = (const float4*)(W1l + lane * D_IN);
        const float4* v = (const float4*)xs[local];
        float acc = 0.0f;
        #pragma unroll
        for (int k = 0; k < D_IN / 4; ++k) {
            float4 a = w[k], b = v[k];
            acc += a.x * b.x + a.y * b.y + a.z * b.z + a.w * b.w;
        }
        xl[(size_t)node * D_H + lane] = f32_to_bf16_rne(acc);
    }
}

// ---------------- Layer 1: gather(mean of xl) + root + relu ----------------
// 1 wave/node; 12 groups x 5 lanes; lane t owns one 16B chunk (8 bf16) of the
// 40-bf16 row; 2x unroll -> 2 dwordx4 loads in flight, 24 neighbors/iter.
__global__ void gather_node1(const float* __restrict__ x,
                             const u32* __restrict__ xlp,
                             const int* __restrict__ off,
                             const int* __restrict__ csr,
                             const float* __restrict__ b1,
                             const float* __restrict__ W1r,
                             float* __restrict__ h, int n) {
    __shared__ __align__(16) float xs[4][D_IN];
    __shared__ __align__(16) float part[4][12][D_H];
    int local = threadIdx.x >> 6;
    int lane  = threadIdx.x & 63;
    int node  = blockIdx.x * 4 + local;
    int g = lane / 5;          // 0..12 (g==12 -> idle lanes 60..63)
    int t = lane - g * 5;      // 0..4
    int deg = 0;
    const uint4* rows = (const uint4*)xlp;   // 5 uint4 per node row
    if (node < n) {
        int o0 = off[node], o1 = off[node + 1];
        deg = o1 - o0;
        xs[local][lane] = x[(size_t)node * D_IN + lane];
        float a0[8] = {0,0,0,0,0,0,0,0};
        float a1[8] = {0,0,0,0,0,0,0,0};
        for (int base = o0; base < o1; base += 64) {
            int cnt = min(64, o1 - base);
            int idx = (base + lane < o1) ? csr[base + lane] : 0;
            if (g < 12) {
                for (int j = 0; j < cnt; j += 24) {
                    int j0 = j + g, j1 = j + 12 + g;
                    int s0 = __shfl(idx, j0);
                    int s1 = __shfl(idx, j1);
                    uint4 w0 = rows[(size_t)s0 * 5 + t];
                    uint4 w1 = rows[(size_t)s1 * 5 + t];
                    if (j0 < cnt) accum8(a0, w0);
                    if (j1 < cnt) accum8(a1, w1);
                }
            }
        }
        if (g < 12) {
            #pragma unroll
            for (int k = 0; k < 8; ++k) a0[k] += a1[k];
            float* p = &part[local][g][t * 8];
            ((float4*)p)[0] = make_float4(a0[0], a0[1], a0[2], a0[3]);
            ((float4*)p)[1] = make_float4(a0[4], a0[5], a0[6], a0[7]);
        }
    }
    __syncthreads();
    if (node < n && lane < D_H) {
        float inv = 1.0f / fmaxf((float)deg, 1.0f);
        float agg = 0.0f;
        #pragma unroll
        for (int gg = 0; gg < 12; ++gg) agg += part[local][gg][lane];
        float acc = b1[lane] + agg * inv;
        const float4* wr = (const float4*)(W1r + lane * D_IN);
        const float4* xr = (const float4*)xs[local];
        #pragma unroll
        for (int k = 0; k < D_IN / 4; ++k) {
            float4 w = wr[k], v = xr[k];
            acc += w.x * v.x + w.y * v.y + w.z * v.z + w.w * v.w;
        }
        h[(size_t)node * D_H + lane] = fmaxf(acc, 0.0f);
    }
}

// ---------------- pre2: h2 = bf16(h @ W2l^T) ----------------
__global__ void pre2(const float* __restrict__ h, const float* __restrict__ W2l,
                     u16* __restrict__ h2, int n) {
    __shared__ __align__(16) float hs[4][D_H];
    int local = threadIdx.x >> 6;
    int lane  = threadIdx.x & 63;
    int node  = blockIdx.x * 4 + local;
    if (node < n && lane < D_H) hs[local][lane] = h[(size_t)node * D_H + lane];
    __syncthreads();
    if (node < n && lane < D_OUT) {
        const float* w = W2l + lane * D_H;
        float acc = 0.0f;
        #pragma unroll
        for (int k = 0; k < D_H; ++k) acc += w[k] * hs[local][k];
        h2[(size_t)node * D_OUT + lane] = f32_to_bf16_rne(acc);
    }
}

// ---------------- Layer 2: gather(mean of h2) + root + log_softmax ----------
// 21 groups x 3 lanes; row = 24 bf16 = 3 uint4; 2x unroll -> 42 neighbors/iter.
__global__ void gather_node2(const float* __restrict__ h,
                             const u32* __restrict__ h2p,
                             const int* __restrict__ off,
                             const int* __restrict__ csr,
                             const float* __restrict__ b2,
                             const float* __restrict__ W2r,
                             float* __restrict__ out, int n) {
    __shared__ __align__(16) float hs[4][D_H];
    __shared__ __align__(16) float part[4][21][D_OUT];
    __shared__ float os[4][D_OUT];
    int local = threadIdx.x >> 6;
    int lane  = threadIdx.x & 63;
    int node  = blockIdx.x * 4 + local;
    int g = lane / 3;          // 0..21 (g==21 -> idle lane 63)
    int t = lane - g * 3;      // 0..2
    int deg = 0;
    const uint4* rows = (const uint4*)h2p;   // 3 uint4 per node row
    if (node < n) {
        int o0 = off[node], o1 = off[node + 1];
        deg = o1 - o0;
        if (lane < D_H) hs[local][lane] = h[(size_t)node * D_H + lane];
        float a0[8] = {0,0,0,0,0,0,0,0};
        float a1[8] = {0,0,0,0,0,0,0,0};
        for (int base = o0; base < o1; base += 64) {
            int cnt = min(64, o1 - base);
            int idx = (base + lane < o1) ? csr[base + lane] : 0;
            if (g < 21) {
                for (int j = 0; j < cnt; j += 42) {
                    int j0 = j + g, j1 = j + 21 + g;
                    int s0 = __shfl(idx, j0);
                    int s1 = __shfl(idx, j1);
                    uint4 w0 = rows[(size_t)s0 * 3 + t];
                    uint4 w1 = rows[(size_t)s1 * 3 + t];
                    if (j0 < cnt) accum8(a0, w0);
                    if (j1 < cnt) accum8(a1, w1);
                }
            }
        }
        if (g < 21) {
            #pragma unroll
            for (int k = 0; k < 8; ++k) a0[k] += a1[k];
            float* p = &part[local][g][t * 8];
            ((float4*)p)[0] = make_float4(a0[0], a0[1], a0[2], a0[3]);
            ((float4*)p)[1] = make_float4(a0[4], a0[5], a0[6], a0[7]);
        }
    }
    __syncthreads();
    if (node < n && lane < D_OUT) {
        float inv = 1.0f / fmaxf((float)deg, 1.0f);
        float agg = 0.0f;
        #pragma unroll
        for (int gg = 0; gg < 21; ++gg) agg += part[local][gg][lane];
        float acc = b2[lane] + agg * inv;
        const float* w = W2r + lane * D_H;
        #pragma unroll
        for (int k = 0; k < D_H; ++k) acc += w[k] * hs[local][k];
        os[local][lane] = acc;
    }
    __syncthreads();
    if (node < n && lane < D_OUT) {
        float m = -INFINITY;
        #pragma unroll
        for (int k = 0; k < D_OUT; ++k) m = fmaxf(m, os[local][k]);
        float se = 0.0f;
        #pragma unroll
        for (int k = 0; k < D_OUT; ++k) se += expf(os[local][k] - m);
        out[(size_t)node * D_OUT + lane] = os[local][lane] - m - logf(se);
    }
}

extern "C" void kernel_launch(void* const* d_in, const int* in_sizes, int n_in,
                              void* d_out, int out_size, void* d_ws, size_t ws_size,
                              hipStream_t stream) {
    const float* x   = (const float*)d_in[0];
    const int*   ei  = (const int*)d_in[1];
    const float* W1l = (const float*)d_in[2];
    const float* b1  = (const float*)d_in[3];
    const float* W1r = (const float*)d_in[4];
    const float* W2l = (const float*)d_in[5];
    const float* b2  = (const float*)d_in[6];
    const float* W2r = (const float*)d_in[7];
    float* out = (float*)d_out;

    const int n = in_sizes[0] / D_IN;      // 100000
    const int E = in_sizes[1] / 2;         // 3200000
    const int* src = ei;
    const int* dst = ei + E;
    const int nb = (n + 255) / 256;

    // Workspace layout (16B-aligned chunks), total ~38 MB:
    //  h   : n*40 f32   = 16.0 MB
    //  xl  : n*40 bf16  =  8.0 MB   (h2 aliases xl — xl dead after gather_node1)
    //  off : (n+1) i32
    //  deg : n i32
    //  cur : n i32
    //  bsum: nb i32
    //  csr : E i32      = 12.8 MB
    char* ws = (char*)d_ws;
    float* h    = (float*)ws;        ws += (size_t)n * D_H * 4;
    u16*   xl   = (u16*)ws;
    u16*   h2   = (u16*)ws;          ws += (size_t)n * D_H * 2;
    int*   off  = (int*)ws;          ws += (((size_t)(n + 1) * 4 + 15) & ~15ull);
    int*   deg  = (int*)ws;          ws += (size_t)n * 4;
    int*   cur  = (int*)ws;          ws += (size_t)n * 4;
    int*   bsum = (int*)ws;          ws += (((size_t)nb * 4 + 15) & ~15ull);
    int*   csr  = (int*)ws;

    hipMemsetAsync(deg, 0, (size_t)n * 2 * 4, stream);   // deg + cur contiguous

    hist_kernel<<<(E + 255) / 256, 256, 0, stream>>>(dst, deg, E);
    scan_blocks<<<nb, 256, 0, stream>>>(deg, off, bsum, n);
    scan_tops<<<1, 64, 0, stream>>>(bsum, nb, off, n);
    add_offsets<<<(n + 255) / 256, 256, 0, stream>>>(off, bsum, n);
    placement<<<(E + 255) / 256, 256, 0, stream>>>(src, dst, off, cur, csr, E);

    pre1<<<(n + 3) / 4, 256, 0, stream>>>(x, W1l, xl, n);
    gather_node1<<<(n + 3) / 4, 256, 0, stream>>>(x, (const u32*)xl, off, csr,
                                                  b1, W1r, h, n);
    pre2<<<(n + 3) / 4, 256, 0, stream>>>(h, W2l, h2, n);
    gather_node2<<<(n + 3) / 4, 256, 0, stream>>>(h, (const u32*)h2, off, csr,
                                                  b2, W2r, out, n);
}

// Round 5
// 692.417 us; speedup vs baseline: 7.4173x; 1.2548x over previous
//
#include <hip/hip_runtime.h>
#include <math.h>

#define D_IN 64
#define D_H 40
#define D_OUT 24

typedef unsigned int u32;
typedef unsigned short u16;

// ---------------- CSR build ----------------
// Histogram + per-edge rank in one pass: rank[i] = old count of dst[i].
__global__ void hist_rank(const int* __restrict__ dst, int* __restrict__ deg,
                          int* __restrict__ rank, int E) {
    int i = blockIdx.x * blockDim.x + threadIdx.x;
    int b = i * 4;
    if (b + 3 < E) {
        int4 d = ((const int4*)dst)[i];
        int4 r;
        r.x = atomicAdd(&deg[d.x], 1);
        r.y = atomicAdd(&deg[d.y], 1);
        r.z = atomicAdd(&deg[d.z], 1);
        r.w = atomicAdd(&deg[d.w], 1);
        ((int4*)rank)[i] = r;
    } else {
        for (int k = b; k < E; ++k) rank[k] = atomicAdd(&deg[dst[k]], 1);
    }
}

__global__ void scan_blocks(const int* __restrict__ deg, int* __restrict__ off,
                            int* __restrict__ bsum, int n) {
    __shared__ int s[256];
    int tx = threadIdx.x;
    int i = blockIdx.x * 256 + tx;
    int v = (i < n) ? deg[i] : 0;
    s[tx] = v;
    __syncthreads();
    for (int d = 1; d < 256; d <<= 1) {
        int t = (tx >= d) ? s[tx - d] : 0;
        __syncthreads();
        s[tx] += t;
        __syncthreads();
    }
    if (i < n) off[i] = s[tx] - v;           // exclusive within block
    if (tx == 255) bsum[blockIdx.x] = s[255];
}

__global__ void scan_tops(int* __restrict__ bsum, int nb, int* __restrict__ off, int n) {
    int lane = threadIdx.x & 63;
    int carry = 0;
    for (int base = 0; base < nb; base += 64) {
        int i = base + lane;
        int orig = (i < nb) ? bsum[i] : 0;
        int v = orig;
        #pragma unroll
        for (int d = 1; d < 64; d <<= 1) {
            int t = __shfl_up(v, d);
            if (lane >= d) v += t;
        }
        if (i < nb) bsum[i] = carry + v - orig;  // exclusive
        carry += __shfl(v, 63);
    }
    if (lane == 0) off[n] = carry;
}

__global__ void add_offsets(int* __restrict__ off, const int* __restrict__ bsum, int n) {
    int i = blockIdx.x * blockDim.x + threadIdx.x;
    if (i < n) off[i] += bsum[i >> 8];
}

// Atomic-free placement: pos = off[dst] + rank. Pure scatter store.
__global__ void placement(const int* __restrict__ src, const int* __restrict__ dst,
                          const int* __restrict__ rank, const int* __restrict__ off,
                          int* __restrict__ csr, int E) {
    int i = blockIdx.x * blockDim.x + threadIdx.x;
    int b = i * 4;
    if (b + 3 < E) {
        int4 s = ((const int4*)src)[i];
        int4 d = ((const int4*)dst)[i];
        int4 r = ((const int4*)rank)[i];
        csr[off[d.x] + r.x] = s.x;
        csr[off[d.y] + r.y] = s.y;
        csr[off[d.z] + r.z] = s.z;
        csr[off[d.w] + r.w] = s.w;
    } else {
        for (int k = b; k < E; ++k) csr[off[dst[k]] + rank[k]] = src[k];
    }
}

// ---------------- bf16 helpers ----------------
__device__ inline u16 f32_to_bf16_rne(float f) {
    u32 u = __float_as_uint(f);
    u += 0x7fffu + ((u >> 16) & 1u);
    return (u16)(u >> 16);
}

// accumulate 8 bf16 (packed in uint4) into f32 acc[8]
__device__ inline void accum8(float* a, uint4 w) {
    a[0] += __uint_as_float(w.x << 16);
    a[1] += __uint_as_float(w.x & 0xffff0000u);
    a[2] += __uint_as_float(w.y << 16);
    a[3] += __uint_as_float(w.y & 0xffff0000u);
    a[4] += __uint_as_float(w.z << 16);
    a[5] += __uint_as_float(w.z & 0xffff0000u);
    a[6] += __uint_as_float(w.w << 16);
    a[7] += __uint_as_float(w.w & 0xffff0000u);
}

// ---------------- pre1: xl = bf16(x @ W1l^T) ----------------
__global__ void pre1(const float* __restrict__ x, const float* __restrict__ W1l,
                     u16* __restrict__ xl, int n) {
    __shared__ __align__(16) float xs[4][D_IN];
    int local = threadIdx.x >> 6;
    int lane  = threadIdx.x & 63;
    int node  = blockIdx.x * 4 + local;
    if (node < n) xs[local][lane] = x[(size_t)node * D_IN + lane];
    __syncthreads();
    if (node < n && lane < D_H) {
        const float4* w = (const float4*)(W1l + lane * D_IN);
        const float4* v = (const float4*)xs[local];
        float acc = 0.0f;
        #pragma unroll
        for (int k = 0; k < D_IN / 4; ++k) {
            float4 a = w[k], b = v[k];
            acc += a.x * b.x + a.y * b.y + a.z * b.z + a.w * b.w;
        }
        xl[(size_t)node * D_H + lane] = f32_to_bf16_rne(acc);
    }
}

// ---------------- Layer 1: gather(mean of xl) + root + relu ----------------
__global__ void gather_node1(const float* __restrict__ x,
                             const u32* __restrict__ xlp,
                             const int* __restrict__ off,
                             const int* __restrict__ csr,
                             const float* __restrict__ b1,
                             const float* __restrict__ W1r,
                             float* __restrict__ h, int n) {
    __shared__ __align__(16) float xs[4][D_IN];
    __shared__ __align__(16) float part[4][12][D_H];
    int local = threadIdx.x >> 6;
    int lane  = threadIdx.x & 63;
    int node  = blockIdx.x * 4 + local;
    int g = lane / 5;          // 0..12 (g==12 -> idle lanes 60..63)
    int t = lane - g * 5;      // 0..4
    int deg = 0;
    const uint4* rows = (const uint4*)xlp;   // 5 uint4 per node row
    if (node < n) {
        int o0 = off[node], o1 = off[node + 1];
        deg = o1 - o0;
        xs[local][lane] = x[(size_t)node * D_IN + lane];
        float a0[8] = {0,0,0,0,0,0,0,0};
        float a1[8] = {0,0,0,0,0,0,0,0};
        for (int base = o0; base < o1; base += 64) {
            int cnt = min(64, o1 - base);
            int idx = (base + lane < o1) ? csr[base + lane] : 0;
            if (g < 12) {
                for (int j = 0; j < cnt; j += 24) {
                    int j0 = j + g, j1 = j + 12 + g;
                    int s0 = __shfl(idx, j0);
                    int s1 = __shfl(idx, j1);
                    uint4 w0 = rows[(size_t)s0 * 5 + t];
                    uint4 w1 = rows[(size_t)s1 * 5 + t];
                    if (j0 < cnt) accum8(a0, w0);
                    if (j1 < cnt) accum8(a1, w1);
                }
            }
        }
        if (g < 12) {
            #pragma unroll
            for (int k = 0; k < 8; ++k) a0[k] += a1[k];
            float* p = &part[local][g][t * 8];
            ((float4*)p)[0] = make_float4(a0[0], a0[1], a0[2], a0[3]);
            ((float4*)p)[1] = make_float4(a0[4], a0[5], a0[6], a0[7]);
        }
    }
    __syncthreads();
    if (node < n && lane < D_H) {
        float inv = 1.0f / fmaxf((float)deg, 1.0f);
        float agg = 0.0f;
        #pragma unroll
        for (int gg = 0; gg < 12; ++gg) agg += part[local][gg][lane];
        float acc = b1[lane] + agg * inv;
        const float4* wr = (const float4*)(W1r + lane * D_IN);
        const float4* xr = (const float4*)xs[local];
        #pragma unroll
        for (int k = 0; k < D_IN / 4; ++k) {
            float4 w = wr[k], v = xr[k];
            acc += w.x * v.x + w.y * v.y + w.z * v.z + w.w * v.w;
        }
        h[(size_t)node * D_H + lane] = fmaxf(acc, 0.0f);
    }
}

// ---------------- pre2: h2 = bf16(h @ W2l^T) ----------------
__global__ void pre2(const float* __restrict__ h, const float* __restrict__ W2l,
                     u16* __restrict__ h2, int n) {
    __shared__ __align__(16) float hs[4][D_H];
    int local = threadIdx.x >> 6;
    int lane  = threadIdx.x & 63;
    int node  = blockIdx.x * 4 + local;
    if (node < n && lane < D_H) hs[local][lane] = h[(size_t)node * D_H + lane];
    __syncthreads();
    if (node < n && lane < D_OUT) {
        const float* w = W2l + lane * D_H;
        float acc = 0.0f;
        #pragma unroll
        for (int k = 0; k < D_H; ++k) acc += w[k] * hs[local][k];
        h2[(size_t)node * D_OUT + lane] = f32_to_bf16_rne(acc);
    }
}

// ---------------- Layer 2: gather(mean of h2) + root + log_softmax ----------
__global__ void gather_node2(const float* __restrict__ h,
                             const u32* __restrict__ h2p,
                             const int* __restrict__ off,
                             const int* __restrict__ csr,
                             const float* __restrict__ b2,
                             const float* __restrict__ W2r,
                             float* __restrict__ out, int n) {
    __shared__ __align__(16) float hs[4][D_H];
    __shared__ __align__(16) float part[4][21][D_OUT];
    __shared__ float os[4][D_OUT];
    int local = threadIdx.x >> 6;
    int lane  = threadIdx.x & 63;
    int node  = blockIdx.x * 4 + local;
    int g = lane / 3;          // 0..21 (g==21 -> idle lane 63)
    int t = lane - g * 3;      // 0..2
    int deg = 0;
    const uint4* rows = (const uint4*)h2p;   // 3 uint4 per node row
    if (node < n) {
        int o0 = off[node], o1 = off[node + 1];
        deg = o1 - o0;
        if (lane < D_H) hs[local][lane] = h[(size_t)node * D_H + lane];
        float a0[8] = {0,0,0,0,0,0,0,0};
        float a1[8] = {0,0,0,0,0,0,0,0};
        for (int base = o0; base < o1; base += 64) {
            int cnt = min(64, o1 - base);
            int idx = (base + lane < o1) ? csr[base + lane] : 0;
            if (g < 21) {
                for (int j = 0; j < cnt; j += 42) {
                    int j0 = j + g, j1 = j + 21 + g;
                    int s0 = __shfl(idx, j0);
                    int s1 = __shfl(idx, j1);
                    uint4 w0 = rows[(size_t)s0 * 3 + t];
                    uint4 w1 = rows[(size_t)s1 * 3 + t];
                    if (j0 < cnt) accum8(a0, w0);
                    if (j1 < cnt) accum8(a1, w1);
                }
            }
        }
        if (g < 21) {
            #pragma unroll
            for (int k = 0; k < 8; ++k) a0[k] += a1[k];
            float* p = &part[local][g][t * 8];
            ((float4*)p)[0] = make_float4(a0[0], a0[1], a0[2], a0[3]);
            ((float4*)p)[1] = make_float4(a0[4], a0[5], a0[6], a0[7]);
        }
    }
    __syncthreads();
    if (node < n && lane < D_OUT) {
        float inv = 1.0f / fmaxf((float)deg, 1.0f);
        float agg = 0.0f;
        #pragma unroll
        for (int gg = 0; gg < 21; ++gg) agg += part[local][gg][lane];
        float acc = b2[lane] + agg * inv;
        const float* w = W2r + lane * D_H;
        #pragma unroll
        for (int k = 0; k < D_H; ++k) acc += w[k] * hs[local][k];
        os[local][lane] = acc;
    }
    __syncthreads();
    if (node < n && lane < D_OUT) {
        float m = -INFINITY;
        #pragma unroll
        for (int k = 0; k < D_OUT; ++k) m = fmaxf(m, os[local][k]);
        float se = 0.0f;
        #pragma unroll
        for (int k = 0; k < D_OUT; ++k) se += expf(os[local][k] - m);
        out[(size_t)node * D_OUT + lane] = os[local][lane] - m - logf(se);
    }
}

extern "C" void kernel_launch(void* const* d_in, const int* in_sizes, int n_in,
                              void* d_out, int out_size, void* d_ws, size_t ws_size,
                              hipStream_t stream) {
    const float* x   = (const float*)d_in[0];
    const int*   ei  = (const int*)d_in[1];
    const float* W1l = (const float*)d_in[2];
    const float* b1  = (const float*)d_in[3];
    const float* W1r = (const float*)d_in[4];
    const float* W2l = (const float*)d_in[5];
    const float* b2  = (const float*)d_in[6];
    const float* W2r = (const float*)d_in[7];
    float* out = (float*)d_out;

    const int n = in_sizes[0] / D_IN;      // 100000
    const int E = in_sizes[1] / 2;         // 3200000
    const int* src = ei;
    const int* dst = ei + E;
    const int nb = (n + 255) / 256;

    // Workspace layout (~37.6 MB):
    //  h    : n*40 f32  = 16.0 MB   (rank aliases h: rank dead before gather_node1)
    //  xl   : n*40 bf16 =  8.0 MB   (h2 aliases xl: xl dead before pre2)
    //  off  : (n+1) i32
    //  deg  : n i32
    //  bsum : nb i32
    //  csr  : E i32     = 12.8 MB
    char* ws = (char*)d_ws;
    float* h    = (float*)ws;
    int*   rank = (int*)ws;          ws += (size_t)n * D_H * 4;
    u16*   xl   = (u16*)ws;
    u16*   h2   = (u16*)ws;          ws += (size_t)n * D_H * 2;
    int*   off  = (int*)ws;          ws += (((size_t)(n + 1) * 4 + 15) & ~15ull);
    int*   deg  = (int*)ws;          ws += (size_t)n * 4;
    int*   bsum = (int*)ws;          ws += (((size_t)nb * 4 + 15) & ~15ull);
    int*   csr  = (int*)ws;

    hipMemsetAsync(deg, 0, (size_t)n * 4, stream);

    const int E4 = (E + 3) / 4;
    hist_rank<<<(E4 + 255) / 256, 256, 0, stream>>>(dst, deg, rank, E);
    scan_blocks<<<nb, 256, 0, stream>>>(deg, off, bsum, n);
    scan_tops<<<1, 64, 0, stream>>>(bsum, nb, off, n);
    add_offsets<<<(n + 255) / 256, 256, 0, stream>>>(off, bsum, n);
    placement<<<(E4 + 255) / 256, 256, 0, stream>>>(src, dst, rank, off, csr, E);

    pre1<<<(n + 3) / 4, 256, 0, stream>>>(x, W1l, xl, n);
    gather_node1<<<(n + 3) / 4, 256, 0, stream>>>(x, (const u32*)xl, off, csr,
                                                  b1, W1r, h, n);
    pre2<<<(n + 3) / 4, 256, 0, stream>>>(h, W2l, h2, n);
    gather_node2<<<(n + 3) / 4, 256, 0, stream>>>(h, (const u32*)h2, off, csr,
                                                  b2, W2r, out, n);
}